// Round 8
// baseline (1927.995 us; speedup 1.0000x reference)
//
#include <hip/hip_runtime.h>
#include <cstdint>

#define TT 128

typedef _Float16 f16;
typedef _Float16 f16x8 __attribute__((ext_vector_type(8)));
typedef float f32x4 __attribute__((ext_vector_type(4)));
typedef unsigned int u32;
typedef unsigned long long u64;

// ---- workspace layout (bytes) ----
// [0,1024): 16 per-group arrival counters, one per 64B line
#define OFF_H0    16384                 // h slabs: [2 par][16 g][32 cg][8 row][32B] = 256KB
#define OFF_H1    (OFF_H0 + 262144)
#define OFF_D0    (OFF_H1 + 262144)
#define OFF_D1    (OFF_D0 + 262144)
#define OFF_XH    (OFF_D1 + 262144)     // x f16: [T][16 g][8 row][128B] = 2MB
#define OFF_HS    (OFF_XH + 2097152)    // dec out: [T][128 row][1KB] = 16MB

// ---- LDS ----
#define L_SB   12288      // SA: h0 slab [32 cg][8 row][48B] = 12288; SB same
#define L_TOT  65536      // fc overlay [64][1024B] needs 64KB

#define MFMA16(a,b,c) __builtin_amdgcn_mfma_f32_16x16x32_f16((a),(b),(c),0,0,0)

__device__ __forceinline__ float sigm(float x){ return 1.f/(1.f+__expf(-x)); }
__device__ __forceinline__ float tanhft(float x){ return 1.f - 2.f/(__expf(2.f*x)+1.f); }

// one B-fragment (8 f16 along K at gate-row srow) from fp32 weights
__device__ __forceinline__ f16x8 wfrag(const float* __restrict__ src, int K, int srow,
                                       int k, int j){
  const float* p = src + srow*K + (k<<5) + (j<<3);
  float4 v0 = *(const float4*)p;
  float4 v1 = *(const float4*)(p+4);
  f16x8 r;
  r[0]=(f16)v0.x; r[1]=(f16)v0.y; r[2]=(f16)v0.z; r[3]=(f16)v0.w;
  r[4]=(f16)v1.x; r[5]=(f16)v1.y; r[6]=(f16)v1.z; r[7]=(f16)v1.w;
  return r;
}

// stage one 8KB h slab (global [32cg][8row][32B], written by agent atomics) into
// LDS [32cg][8row][48B] via agent-relaxed atomic b64 loads (coherent, no fence).
__device__ __forceinline__ void stage1(const char* R, char* S, int tid){
  const int cgs = tid >> 3, row = tid & 7;
  const char* gp = R + cgs*256 + row*32;
  char* sp = S + cgs*384 + row*48;
  u64 t0[4];
#pragma unroll
  for (int i = 0; i < 4; ++i)
    t0[i] = __hip_atomic_load((const u64*)(gp + i*8),
                              __ATOMIC_RELAXED, __HIP_MEMORY_SCOPE_AGENT);
#pragma unroll
  for (int i = 0; i < 4; ++i)
    *(u64*)(sp + i*8) = t0[i];
}

__device__ __forceinline__ void stage2(const char* R0, const char* R1,
                                       char* SA, char* SB, int tid){
  const int cgs = tid >> 3, row = tid & 7;
  const char* g0 = R0 + cgs*256 + row*32;
  const char* g1 = R1 + cgs*256 + row*32;
  char* s0 = SA + cgs*384 + row*48;
  char* s1 = SB + cgs*384 + row*48;
  u64 t0[4], t1[4];
#pragma unroll
  for (int i = 0; i < 4; ++i)
    t0[i] = __hip_atomic_load((const u64*)(g0 + i*8),
                              __ATOMIC_RELAXED, __HIP_MEMORY_SCOPE_AGENT);
#pragma unroll
  for (int i = 0; i < 4; ++i)
    t1[i] = __hip_atomic_load((const u64*)(g1 + i*8),
                              __ATOMIC_RELAXED, __HIP_MEMORY_SCOPE_AGENT);
#pragma unroll
  for (int i = 0; i < 4; ++i) *(u64*)(s0 + i*8) = t0[i];
#pragma unroll
  for (int i = 0; i < 4; ++i) *(u64*)(s1 + i*8) = t1[i];
}

// group barrier (32 WGs) via single-line monotonic counter. No fences:
// data reads are agent-scope atomics (coherent by construction).
__device__ __forceinline__ void gbar(u32* cnt, int tid, u32 target32){
  __syncthreads();
  if (tid == 0){
    u32 c = __hip_atomic_fetch_add(cnt, 1, __ATOMIC_RELAXED, __HIP_MEMORY_SCOPE_AGENT) + 1;
    while (c < target32){
      __builtin_amdgcn_s_sleep(1);
      c = __hip_atomic_load(cnt, __ATOMIC_RELAXED, __HIP_MEMORY_SCOPE_AGENT);
    }
  }
  __syncthreads();
}

// x [B][T][64] f32 -> [T][g 16][row 8][128B] f16
__global__ void cvt_x(const float* __restrict__ x, char* __restrict__ ws){
  int idx = blockIdx.x*256 + threadIdx.x;        // 131072 units of 8 f32
  int chunk = idx & 7, b = (idx >> 3) & 127, t = idx >> 10;
  const float* s = x + (((b<<7) + t)<<6) + (chunk<<3);
  float4 v0 = *(const float4*)s, v1 = *(const float4*)(s+4);
  f16x8 h;
  h[0]=(f16)v0.x; h[1]=(f16)v0.y; h[2]=(f16)v0.z; h[3]=(f16)v0.w;
  h[4]=(f16)v1.x; h[5]=(f16)v1.y; h[6]=(f16)v1.z; h[7]=(f16)v1.w;
  *(f16x8*)(ws + OFF_XH + ((t<<4) + (b>>3))*1024 + (b&7)*128 + (chunk<<4)) = h;
}

__global__ __launch_bounds__(256, 2) void lstm_persist(
    const float* __restrict__ eWih0, const float* __restrict__ eWhh0,
    const float* __restrict__ ebi0,  const float* __restrict__ ebh0,
    const float* __restrict__ eWih1, const float* __restrict__ eWhh1,
    const float* __restrict__ ebi1,  const float* __restrict__ ebh1,
    const float* __restrict__ dWih0, const float* __restrict__ dWhh0,
    const float* __restrict__ dbi0,  const float* __restrict__ dbh0,
    const float* __restrict__ dWih1, const float* __restrict__ dWhh1,
    const float* __restrict__ dbi1,  const float* __restrict__ dbh1,
    const float* __restrict__ fcW,   const float* __restrict__ fcb,
    float* __restrict__ out, char* __restrict__ ws)
{
  __shared__ __align__(16) char lds[L_TOT];
  const int tid  = threadIdx.x;
  const int wg   = blockIdx.x;
  const int g    = wg >> 5;            // batch group (8 rows); co-tenant WGs differ in g
  const int cg   = wg & 31;            // column group (16 hcols = 64 gate cols)
  const int b0   = g << 3;
  const int lane = tid & 63, w = tid >> 6;
  const int j    = lane >> 4;                    // k-run (0..3)
  const int arow = (lane & 15) & 7;              // A row (8 valid, replicated)
  const int bq   = lane & 15;                    // B row: (hc local = bq>>2, gate = bq&3)
  const int srow = ((bq&3)<<9) + (cg<<4) + (w<<2) + (bq>>2);   // global gate row
  const int lq   = lane & 3;
  const int hcc  = (lane >> 2) & 3;              // cell hcol within wave quad-group
  const int row_c = ((lane>>4)<<2) + lq;         // cell-owned batch row (valid if lane<32)
  const bool vrow = (lane < 32);                 // rows 0..7 valid

  u32* cnt = (u32*)(ws + (g<<6));                // one counter line per group
  char* H0 = ws + OFF_H0;  char* H1 = ws + OFF_H1;
  char* D0 = ws + OFF_D0;  char* D1 = ws + OFF_D1;
  const char* XH = ws + OFF_XH;
  char* HS = ws + OFF_HS;
  char* SA = lds + 0; char* SB = lds + L_SB;

  // A-frag LDS base: addr = k*768 + (j>>1)*384 + arow*48 + (j&1)*16
  const int abase = ((j>>1)*384) + arow*48 + ((j&1)<<4);
  // h store offset within 8KB slab: [cg][row][32B], wave piece at w*8
  const int hst = cg*256 + row_c*32 + (w<<3);

  // ---- encoder weights -> registers ----
  f16x8 wA[16], wB[16], wC[16], wX0, wX1;
#pragma unroll
  for (int k = 0; k < 16; ++k){
    wA[k] = wfrag(eWhh0, 512, srow, k, j);
    wB[k] = wfrag(eWih1, 512, srow, k, j);
    wC[k] = wfrag(eWhh1, 512, srow, k, j);
  }
  wX0 = wfrag(eWih0, 64, srow, 0, j);
  wX1 = wfrag(eWih0, 64, srow, 1, j);
  float B0r[4], B1r[4];
#pragma unroll
  for (int e = 0; e < 4; ++e){
    int bi = (e<<9) + (cg<<4) + (w<<2) + hcc;
    B0r[e] = ebi0[bi] + ebh0[bi];
    B1r[e] = ebi1[bi] + ebh1[bi];
  }

  // quad 4x4 transpose
  auto qtr = [&](f32x4 a) -> f32x4 {
    float s0 = __shfl_xor(a[1],1), s1 = __shfl_xor(a[0],1);
    float s2 = __shfl_xor(a[3],1), s3 = __shfl_xor(a[2],1);
    bool o1 = lane & 1;
    float c0 = o1 ? s0 : a[0];
    float c1 = o1 ? a[1] : s1;
    float c2 = o1 ? s2 : a[2];
    float c3 = o1 ? a[3] : s3;
    float u0 = __shfl_xor(c2,2), u1 = __shfl_xor(c3,2);
    float u2 = __shfl_xor(c0,2), u3 = __shfl_xor(c1,2);
    bool o2 = lane & 2;
    f32x4 t;
    t[0] = o2 ? u0 : c0;
    t[1] = o2 ? u1 : c1;
    t[2] = o2 ? c2 : u2;
    t[3] = o2 ? c3 : u3;
    return t;
  };

  float c0v = 0.f, c1v = 0.f;
  u32 bt = 0;

  // ================= encoder: layers 0+1 pipelined, 1 barrier/step =================
  for (int s = 0; s <= TT; ++s){
    const bool d0 = (s < TT), d1 = (s >= 1);
    const char* R0 = H0 + (((s&1)<<4) + g)*8192;
    const char* R1 = H1 + (((s&1)<<4) + g)*8192;
    char* W0 = H0 + ((((s+1)&1)<<4) + g)*8192;
    char* W1 = H1 + ((((s+1)&1)<<4) + g)*8192;

    stage2(R0, R1, SA, SB, tid);      // coherent atomic loads -> LDS
    f16x8 xa0, xa1;
    if (d0){
      const char* xg = XH + ((s<<4) + g)*1024 + arow*128 + (j<<4);
      xa0 = *(const f16x8*)(xg);
      xa1 = *(const f16x8*)(xg + 64);
    }
    __syncthreads();

    f32x4 acc0 = {0.f,0.f,0.f,0.f}, acc1 = {0.f,0.f,0.f,0.f};
    if (d0){
      acc0 = MFMA16(xa0, wX0, acc0);
      acc0 = MFMA16(xa1, wX1, acc0);
    }
#pragma unroll
    for (int k = 0; k < 16; ++k){
      f16x8 a0 = *(const f16x8*)(SA + k*768 + abase);   // h0 serves BOTH layers
      f16x8 a1 = *(const f16x8*)(SB + k*768 + abase);
      acc0 = MFMA16(a0, wA[k], acc0);
      acc1 = MFMA16(a0, wB[k], acc1);
      acc1 = MFMA16(a1, wC[k], acc1);
    }

    if (d0){
      f32x4 t = qtr(acc0);
      float gi = sigm(t[0]+B0r[0]), gf = sigm(t[1]+B0r[1]);
      float gg = tanhft(t[2]+B0r[2]), go = sigm(t[3]+B0r[3]);
      c0v = gf*c0v + gi*gg;
      float h = go * tanhft(c0v);
      union { f16 hf; unsigned short su; } cv; cv.hf = (f16)h;
      u32 v = cv.su;
      u32 p = v | (((u32)(unsigned short)__shfl_xor((int)v, 4)) << 16);
      u32 q = (u32)__shfl_xor((int)p, 8);
      if (!(lane & 12) && vrow){
        u64 pk = (u64)p | ((u64)q << 32);
        __hip_atomic_store((u64*)(W0 + hst), pk,
                           __ATOMIC_RELAXED, __HIP_MEMORY_SCOPE_AGENT);
      }
    }
    if (d1){
      f32x4 t = qtr(acc1);
      float gi = sigm(t[0]+B1r[0]), gf = sigm(t[1]+B1r[1]);
      float gg = tanhft(t[2]+B1r[2]), go = sigm(t[3]+B1r[3]);
      c1v = gf*c1v + gi*gg;
      float h = go * tanhft(c1v);
      union { f16 hf; unsigned short su; } cv; cv.hf = (f16)h;
      u32 v = cv.su;
      u32 p = v | (((u32)(unsigned short)__shfl_xor((int)v, 4)) << 16);
      u32 q = (u32)__shfl_xor((int)p, 8);
      if (!(lane & 12) && vrow){
        u64 pk = (u64)p | ((u64)q << 32);
        __hip_atomic_store((u64*)(W1 + hst), pk,
                           __ATOMIC_RELAXED, __HIP_MEMORY_SCOPE_AGENT);
      }
    }
    gbar(cnt, tid, (++bt) << 5);
  }

  // ================= zx = z @ dW_ih0 + biases (one-time) =================
  f32x4 zx;
  {
    stage1(H1 + (16 + g)*8192, SA, tid);        // z = final enc1 h, parity 1
    f16x8 wZ[16];
#pragma unroll
    for (int k = 0; k < 16; ++k) wZ[k] = wfrag(dWih0, 512, srow, k, j);
    float zb = dbi0[srow] + dbh0[srow];
    zx[0]=zb; zx[1]=zb; zx[2]=zb; zx[3]=zb;
    __syncthreads();
#pragma unroll
    for (int k = 0; k < 16; ++k)
      zx = MFMA16(*(const f16x8*)(SA + k*768 + abase), wZ[k], zx);
  }

  // ---- decoder weights ----
#pragma unroll
  for (int k = 0; k < 16; ++k){
    wA[k] = wfrag(dWhh0, 512, srow, k, j);
    wB[k] = wfrag(dWih1, 512, srow, k, j);
    wC[k] = wfrag(dWhh1, 512, srow, k, j);
  }
#pragma unroll
  for (int e = 0; e < 4; ++e){
    int bi = (e<<9) + (cg<<4) + (w<<2) + hcc;
    B1r[e] = dbi1[bi] + dbh1[bi];
  }
  c0v = 0.f; c1v = 0.f;

  // ================= decoder =================
  for (int s = 0; s <= TT; ++s){
    const bool d0 = (s < TT), d1 = (s >= 1);
    const char* R0 = D0 + (((s&1)<<4) + g)*8192;
    const char* R1 = D1 + (((s&1)<<4) + g)*8192;
    char* W0 = D0 + ((((s+1)&1)<<4) + g)*8192;
    char* W1 = D1 + ((((s+1)&1)<<4) + g)*8192;

    stage2(R0, R1, SA, SB, tid);
    __syncthreads();

    f32x4 acc0 = zx, acc1 = {0.f,0.f,0.f,0.f};
#pragma unroll
    for (int k = 0; k < 16; ++k){
      f16x8 a0 = *(const f16x8*)(SA + k*768 + abase);
      f16x8 a1 = *(const f16x8*)(SB + k*768 + abase);
      acc0 = MFMA16(a0, wA[k], acc0);
      acc1 = MFMA16(a0, wB[k], acc1);
      acc1 = MFMA16(a1, wC[k], acc1);
    }

    if (d0){
      f32x4 t = qtr(acc0);
      float gi = sigm(t[0]), gf = sigm(t[1]);    // biases folded into zx
      float gg = tanhft(t[2]), go = sigm(t[3]);
      c0v = gf*c0v + gi*gg;
      float h = go * tanhft(c0v);
      union { f16 hf; unsigned short su; } cv; cv.hf = (f16)h;
      u32 v = cv.su;
      u32 p = v | (((u32)(unsigned short)__shfl_xor((int)v, 4)) << 16);
      u32 q = (u32)__shfl_xor((int)p, 8);
      if (!(lane & 12) && vrow){
        u64 pk = (u64)p | ((u64)q << 32);
        __hip_atomic_store((u64*)(W0 + hst), pk,
                           __ATOMIC_RELAXED, __HIP_MEMORY_SCOPE_AGENT);
      }
    }
    if (d1){
      f32x4 t = qtr(acc1);
      float gi = sigm(t[0]+B1r[0]), gf = sigm(t[1]+B1r[1]);
      float gg = tanhft(t[2]+B1r[2]), go = sigm(t[3]+B1r[3]);
      c1v = gf*c1v + gi*gg;
      float h = go * tanhft(c1v);
      union { f16 hf; unsigned short su; } cv; cv.hf = (f16)h;
      u32 v = cv.su;
      u32 p = v | (((u32)(unsigned short)__shfl_xor((int)v, 4)) << 16);
      u32 q = (u32)__shfl_xor((int)p, 8);
      if (!(lane & 12) && vrow){
        u64 pk = (u64)p | ((u64)q << 32);
        __hip_atomic_store((u64*)(W1 + hst), pk,
                           __ATOMIC_RELAXED, __HIP_MEMORY_SCOPE_AGENT);
        // archive for fc: [t][128 rows][1KB]
        __hip_atomic_store((u64*)(HS + (((s-1)<<7) + b0 + row_c)*1024 + cg*32 + (w<<3)), pk,
                           __ATOMIC_RELAXED, __HIP_MEMORY_SCOPE_AGENT);
      }
    }
    gbar(cnt, tid, (++bt) << 5);
  }

  // single acquire fence before plain HS reads
  __builtin_amdgcn_fence(__ATOMIC_ACQUIRE, "agent");
  __syncthreads();

  // ================= fc epilogue =================
  for (int qd = tid; qd < 8192; qd += 256){      // fcW [64][512] f32 -> f16 LDS
    int i = qd >> 7, kq = qd & 127;
    float4 v = *(const float4*)(fcW + (i<<9) + (kq<<2));
    f16* p = (f16*)(lds + (i<<10) + (kq<<3));
    p[0]=(f16)v.x; p[1]=(f16)v.y; p[2]=(f16)v.z; p[3]=(f16)v.w;
  }
  __syncthreads();
  {
    int t  = (cg<<2) + w;                        // 32 cg x 4 waves = 128 timesteps
    int r  = lane >> 3;                          // 8 rows
    int iq = lane & 7;                           // 8 output chunks of 8
    const char* hsrow = HS + (((t<<7) + b0 + r)<<10);
    float acc[8];
#pragma unroll
    for (int ii = 0; ii < 8; ++ii) acc[ii] = 0.f;
    for (int k8 = 0; k8 < 64; ++k8){
      f16x8 hv = *(const f16x8*)(hsrow + (k8<<4));
#pragma unroll
      for (int ii = 0; ii < 8; ++ii){
        f16x8 wv = *(const f16x8*)(lds + (((iq<<3)+ii)<<10) + (k8<<4));
#pragma unroll
        for (int jj = 0; jj < 8; ++jj) acc[ii] += (float)hv[jj] * (float)wv[jj];
      }
    }
#pragma unroll
    for (int ii = 0; ii < 8; ++ii){
      int i = (iq<<3) + ii;
      out[((((b0+r)<<7) + t)<<6) + i] = acc[ii] + fcb[i];
    }
  }
}

extern "C" void kernel_launch(void* const* d_in, const int* in_sizes, int n_in,
                              void* d_out, int out_size, void* d_ws, size_t ws_size,
                              hipStream_t stream){
  const float* x     = (const float*)d_in[0];
  const float* eWih0 = (const float*)d_in[1];
  const float* eWhh0 = (const float*)d_in[2];
  const float* ebi0  = (const float*)d_in[3];
  const float* ebh0  = (const float*)d_in[4];
  const float* eWih1 = (const float*)d_in[5];
  const float* eWhh1 = (const float*)d_in[6];
  const float* ebi1  = (const float*)d_in[7];
  const float* ebh1  = (const float*)d_in[8];
  const float* dWih0 = (const float*)d_in[9];
  const float* dWhh0 = (const float*)d_in[10];
  const float* dbi0  = (const float*)d_in[11];
  const float* dbh0  = (const float*)d_in[12];
  const float* dWih1 = (const float*)d_in[13];
  const float* dWhh1 = (const float*)d_in[14];
  const float* dbi1  = (const float*)d_in[15];
  const float* dbh1  = (const float*)d_in[16];
  const float* fcW   = (const float*)d_in[17];
  const float* fcb   = (const float*)d_in[18];
  char* ws = (char*)d_ws;

  hipMemsetAsync(d_ws, 0, OFF_XH, stream);       // zero counters + all h double-buffers
  cvt_x<<<512, 256, 0, stream>>>(x, ws);
  lstm_persist<<<512, 256, 0, stream>>>(eWih0,eWhh0,ebi0,ebh0,eWih1,eWhh1,ebi1,ebh1,
                                        dWih0,dWhh0,dbi0,dbh0,dWih1,dWhh1,dbi1,dbh1,
                                        fcW,fcb,(float*)d_out,ws);
}

// Round 9
// 1736.679 us; speedup vs baseline: 1.1102x; 1.1102x over previous
//
#include <hip/hip_runtime.h>
#include <cstdint>

#define TT 128

typedef _Float16 f16;
typedef _Float16 f16x8 __attribute__((ext_vector_type(8)));
typedef float f32x4 __attribute__((ext_vector_type(4)));
typedef unsigned int u32;
typedef unsigned long long u64;

// ---- workspace layout (bytes) ----
// [0,1024): 16 per-group arrival counters, one per 64B line (monotonic within launch)
#define OFF_H0    16384                 // h slabs: [2 par][16 g][32 cg][8 row][32B] = 256KB
#define OFF_H1    (OFF_H0 + 262144)
#define OFF_D0    (OFF_H1 + 262144)
#define OFF_D1    (OFF_D0 + 262144)
#define OFF_XH    (OFF_D1 + 262144)     // x f16: [T][16 g][8 row][128B] = 2MB
#define OFF_HS    (OFF_XH + 2097152)    // dec out: [T][128 row][1KB] = 16MB

// ---- LDS ----  two streams x two layer slabs, each [32 cg][8 row][48B] = 12288
#define L_A0   0
#define L_A1   12288
#define L_B0   24576
#define L_B1   36864
#define L_TOT  65536      // fc overlay [64][1024B] reuses whole block in epilogue

#define MFMA16(a,b,c) __builtin_amdgcn_mfma_f32_16x16x32_f16((a),(b),(c),0,0,0)

__device__ __forceinline__ float sigm(float x){ return 1.f/(1.f+__expf(-x)); }
__device__ __forceinline__ float tanhft(float x){ return 1.f - 2.f/(__expf(2.f*x)+1.f); }

// one B-fragment (8 f16 along K at gate-row srow) from fp32 weights
__device__ __forceinline__ f16x8 wfrag(const float* __restrict__ src, int K, int srow,
                                       int k, int j){
  const float* p = src + srow*K + (k<<5) + (j<<3);
  float4 v0 = *(const float4*)p;
  float4 v1 = *(const float4*)(p+4);
  f16x8 r;
  r[0]=(f16)v0.x; r[1]=(f16)v0.y; r[2]=(f16)v0.z; r[3]=(f16)v0.w;
  r[4]=(f16)v1.x; r[5]=(f16)v1.y; r[6]=(f16)v1.z; r[7]=(f16)v1.w;
  return r;
}

// stage issue: coherent agent-scope atomic loads of two 8KB slabs -> regs
__device__ __forceinline__ void sIssue(const char* R0, const char* R1, u64* t, int tid){
  const int cgs = tid >> 3, row = tid & 7;
  const char* g0 = R0 + cgs*256 + row*32;
  const char* g1 = R1 + cgs*256 + row*32;
#pragma unroll
  for (int i = 0; i < 4; ++i)
    t[i] = __hip_atomic_load((const u64*)(g0 + i*8),
                             __ATOMIC_RELAXED, __HIP_MEMORY_SCOPE_AGENT);
#pragma unroll
  for (int i = 0; i < 4; ++i)
    t[4+i] = __hip_atomic_load((const u64*)(g1 + i*8),
                               __ATOMIC_RELAXED, __HIP_MEMORY_SCOPE_AGENT);
}
// stage commit: regs -> LDS [32cg][8row][48B]
__device__ __forceinline__ void sCommit(char* S0, char* S1, const u64* t, int tid){
  const int cgs = tid >> 3, row = tid & 7;
  char* s0 = S0 + cgs*384 + row*48;
  char* s1 = S1 + cgs*384 + row*48;
#pragma unroll
  for (int i = 0; i < 4; ++i) *(u64*)(s0 + i*8) = t[i];
#pragma unroll
  for (int i = 0; i < 4; ++i) *(u64*)(s1 + i*8) = t[4+i];
}

__device__ __forceinline__ void pollw(u32* c, u32 tgt){
  u32 v = __hip_atomic_load(c, __ATOMIC_RELAXED, __HIP_MEMORY_SCOPE_AGENT);
  while (v < tgt){
    __builtin_amdgcn_s_sleep(1);
    v = __hip_atomic_load(c, __ATOMIC_RELAXED, __HIP_MEMORY_SCOPE_AGENT);
  }
}

// x [B][T][64] f32 -> [T][g 16][row 8][128B] f16
__global__ void cvt_x(const float* __restrict__ x, char* __restrict__ ws){
  int idx = blockIdx.x*256 + threadIdx.x;        // 131072 units of 8 f32
  int chunk = idx & 7, b = (idx >> 3) & 127, t = idx >> 10;
  const float* s = x + (((b<<7) + t)<<6) + (chunk<<3);
  float4 v0 = *(const float4*)s, v1 = *(const float4*)(s+4);
  f16x8 h;
  h[0]=(f16)v0.x; h[1]=(f16)v0.y; h[2]=(f16)v0.z; h[3]=(f16)v0.w;
  h[4]=(f16)v1.x; h[5]=(f16)v1.y; h[6]=(f16)v1.z; h[7]=(f16)v1.w;
  *(f16x8*)(ws + OFF_XH + ((t<<4) + (b>>3))*1024 + (b&7)*128 + (chunk<<4)) = h;
}

__global__ __launch_bounds__(256, 1) void lstm_persist(
    const float* __restrict__ eWih0, const float* __restrict__ eWhh0,
    const float* __restrict__ ebi0,  const float* __restrict__ ebh0,
    const float* __restrict__ eWih1, const float* __restrict__ eWhh1,
    const float* __restrict__ ebi1,  const float* __restrict__ ebh1,
    const float* __restrict__ dWih0, const float* __restrict__ dWhh0,
    const float* __restrict__ dbi0,  const float* __restrict__ dbh0,
    const float* __restrict__ dWih1, const float* __restrict__ dWhh1,
    const float* __restrict__ dbi1,  const float* __restrict__ dbh1,
    const float* __restrict__ fcW,   const float* __restrict__ fcb,
    float* __restrict__ out, char* __restrict__ ws)
{
  __shared__ __align__(16) char lds[L_TOT];
  const int tid  = threadIdx.x;
  const int wg   = blockIdx.x;
  const int gA   = wg >> 5;            // stream A group (0..7), 8 rows
  const int gB   = gA + 8;             // stream B group (8..15)
  const int cg   = wg & 31;            // column group (16 hcols = 64 gate cols)
  const int b0A  = gA << 3, b0B = gB << 3;
  const int lane = tid & 63, w = tid >> 6;
  const int j    = lane >> 4;                    // k-run (0..3)
  const int arow = lane & 7;                     // A row (8 valid, replicated)
  const int bq   = lane & 15;                    // B row: (hc local = bq>>2, gate = bq&3)
  const int srow = ((bq&3)<<9) + (cg<<4) + (w<<2) + (bq>>2);   // global gate row
  const int lq   = lane & 3;
  const int hcc  = (lane >> 2) & 3;
  const int row_c = ((lane>>4)<<2) + lq;         // cell-owned row (valid if lane<32)
  const bool vst  = !(lane & 12) && (lane < 32); // store lanes

  u32* cntA = (u32*)(ws + (gA<<6));
  u32* cntB = (u32*)(ws + (gB<<6));
  char* H0 = ws + OFF_H0;  char* H1 = ws + OFF_H1;
  char* D0 = ws + OFF_D0;  char* D1 = ws + OFF_D1;
  const char* XH = ws + OFF_XH;
  char* HS = ws + OFF_HS;
  char* SA0 = lds + L_A0; char* SA1 = lds + L_A1;
  char* SB0 = lds + L_B0; char* SB1 = lds + L_B1;

  // A-frag LDS addr: k*768 + (j>>1)*384 + arow*48 + (j&1)*16
  const int abase = ((j>>1)*384) + arow*48 + ((j&1)<<4);
  const int hst = cg*256 + row_c*32 + (w<<3);    // h store offset in 8KB slab

  // ---- encoder weights -> registers ----
  f16x8 wA[16], wB[16], wC[16], wX0, wX1;
#pragma unroll
  for (int k = 0; k < 16; ++k){
    wA[k] = wfrag(eWhh0, 512, srow, k, j);
    wB[k] = wfrag(eWih1, 512, srow, k, j);
    wC[k] = wfrag(eWhh1, 512, srow, k, j);
  }
  wX0 = wfrag(eWih0, 64, srow, 0, j);
  wX1 = wfrag(eWih0, 64, srow, 1, j);
  float B0r[4], B1r[4];
#pragma unroll
  for (int e = 0; e < 4; ++e){
    int bi = (e<<9) + (cg<<4) + (w<<2) + hcc;
    B0r[e] = ebi0[bi] + ebh0[bi];
    B1r[e] = ebi1[bi] + ebh1[bi];
  }

  // quad 4x4 transpose
  auto qtr = [&](f32x4 a) -> f32x4 {
    float s0 = __shfl_xor(a[1],1), s1 = __shfl_xor(a[0],1);
    float s2 = __shfl_xor(a[3],1), s3 = __shfl_xor(a[2],1);
    bool o1 = lane & 1;
    float c0 = o1 ? s0 : a[0];
    float c1 = o1 ? a[1] : s1;
    float c2 = o1 ? s2 : a[2];
    float c3 = o1 ? a[3] : s3;
    float u0 = __shfl_xor(c2,2), u1 = __shfl_xor(c3,2);
    float u2 = __shfl_xor(c0,2), u3 = __shfl_xor(c1,2);
    bool o2 = lane & 2;
    f32x4 t;
    t[0] = o2 ? u0 : c0;
    t[1] = o2 ? u1 : c1;
    t[2] = o2 ? c2 : u2;
    t[3] = o2 ? c3 : u3;
    return t;
  };

  // MFMA phase (encoder): both layers from staged slabs; x term if d0
  auto Menc = [&](int gX, const char* S0, const char* S1, int s, f32x4& A0, f32x4& A1){
    A0 = f32x4{0.f,0.f,0.f,0.f}; A1 = f32x4{0.f,0.f,0.f,0.f};
    if (s < TT){
      const char* xg = XH + ((s<<4) + gX)*1024 + arow*128 + (j<<4);
      f16x8 xa0 = *(const f16x8*)xg, xa1 = *(const f16x8*)(xg + 64);
      A0 = MFMA16(xa0, wX0, A0);
      A0 = MFMA16(xa1, wX1, A0);
    }
#pragma unroll
    for (int k = 0; k < 16; ++k){
      f16x8 a0 = *(const f16x8*)(S0 + k*768 + abase);
      f16x8 a1 = *(const f16x8*)(S1 + k*768 + abase);
      A0 = MFMA16(a0, wA[k], A0);
      A1 = MFMA16(a0, wB[k], A1);
      A1 = MFMA16(a1, wC[k], A1);
    }
  };
  // MFMA phase (decoder): acc0 starts at zx (z@Wih0 + both biases)
  auto Mdec = [&](const char* S0, const char* S1, f32x4 zxv, f32x4& A0, f32x4& A1){
    A0 = zxv; A1 = f32x4{0.f,0.f,0.f,0.f};
#pragma unroll
    for (int k = 0; k < 16; ++k){
      f16x8 a0 = *(const f16x8*)(S0 + k*768 + abase);
      f16x8 a1 = *(const f16x8*)(S1 + k*768 + abase);
      A0 = MFMA16(a0, wA[k], A0);
      A1 = MFMA16(a0, wB[k], A1);
      A1 = MFMA16(a1, wC[k], A1);
    }
  };

  // cell phase: gates, c/h update, packed 8B agent-scope atomic h stores
  auto Ccell = [&](int s, bool dec, f32x4 A0, f32x4 A1, float& c0, float& c1,
                   char* W0, char* W1, int b0X){
    if (s < TT){
      f32x4 t = qtr(A0);
      float gi, gf, gg, go;
      if (dec){ gi = sigm(t[0]); gf = sigm(t[1]); gg = tanhft(t[2]); go = sigm(t[3]); }
      else    { gi = sigm(t[0]+B0r[0]); gf = sigm(t[1]+B0r[1]);
                gg = tanhft(t[2]+B0r[2]); go = sigm(t[3]+B0r[3]); }
      c0 = gf*c0 + gi*gg;
      float h = go * tanhft(c0);
      union { f16 hf; unsigned short su; } cv; cv.hf = (f16)h;
      u32 v = cv.su;
      u32 p = v | (((u32)(unsigned short)__shfl_xor((int)v, 4)) << 16);
      u32 q = (u32)__shfl_xor((int)p, 8);
      if (vst){
        u64 pk = (u64)p | ((u64)q << 32);
        __hip_atomic_store((u64*)(W0 + hst), pk,
                           __ATOMIC_RELAXED, __HIP_MEMORY_SCOPE_AGENT);
      }
    }
    if (s >= 1){
      f32x4 t = qtr(A1);
      float gi = sigm(t[0]+B1r[0]), gf = sigm(t[1]+B1r[1]);
      float gg = tanhft(t[2]+B1r[2]), go = sigm(t[3]+B1r[3]);
      c1 = gf*c1 + gi*gg;
      float h = go * tanhft(c1);
      union { f16 hf; unsigned short su; } cv; cv.hf = (f16)h;
      u32 v = cv.su;
      u32 p = v | (((u32)(unsigned short)__shfl_xor((int)v, 4)) << 16);
      u32 q = (u32)__shfl_xor((int)p, 8);
      if (vst){
        u64 pk = (u64)p | ((u64)q << 32);
        __hip_atomic_store((u64*)(W1 + hst), pk,
                           __ATOMIC_RELAXED, __HIP_MEMORY_SCOPE_AGENT);
        if (dec)
          __hip_atomic_store((u64*)(HS + (((s-1)<<7) + b0X + row_c)*1024 + cg*32 + (w<<3)), pk,
                             __ATOMIC_RELAXED, __HIP_MEMORY_SCOPE_AGENT);
      }
    }
  };

  float c0A = 0.f, c1A = 0.f, c0B = 0.f, c1B = 0.f;
  u64 tA[8], tB[8];
  f32x4 a0, a1;

  // ================= encoder: 2-stream interleave, 1 rendezvous per half-step =====
  // prologue: stage A step 0 (parity 0 buffers are zeroed -> no poll needed)
  sIssue(H0 + gA*8192, H1 + gA*8192, tA, tid);
  sCommit(SA0, SA1, tA, tid);
  __syncthreads();

  for (int s = 0; s <= TT; ++s){
    // --- half-step A: compute A(s), stage B(s) ---
    Menc(gA, SA0, SA1, s, a0, a1);
    Ccell(s, false, a0, a1, c0A, c1A,
          H0 + ((((s+1)&1)<<4) + gA)*8192, H1 + ((((s+1)&1)<<4) + gA)*8192, b0A);
    __syncthreads();                               // drain A stores
    if (tid == 0)
      (void)__hip_atomic_fetch_add(cntA, 1u, __ATOMIC_RELAXED, __HIP_MEMORY_SCOPE_AGENT);
    if (tid == 64) pollw(cntB, 32u*(u32)s);        // B peers' h(s-1) visible (settled ~1 half-step)
    __syncthreads();
    sIssue(H0 + (((s&1)<<4) + gB)*8192, H1 + (((s&1)<<4) + gB)*8192, tB, tid);
    sCommit(SB0, SB1, tB, tid);
    __syncthreads();

    // --- half-step B: compute B(s), stage A(s+1) ---
    Menc(gB, SB0, SB1, s, a0, a1);
    Ccell(s, false, a0, a1, c0B, c1B,
          H0 + ((((s+1)&1)<<4) + gB)*8192, H1 + ((((s+1)&1)<<4) + gB)*8192, b0B);
    __syncthreads();
    if (tid == 0)
      (void)__hip_atomic_fetch_add(cntB, 1u, __ATOMIC_RELAXED, __HIP_MEMORY_SCOPE_AGENT);
    if (s < TT){
      if (tid == 64) pollw(cntA, 32u*(u32)(s+1));
      __syncthreads();
      sIssue(H0 + ((((s+1)&1)<<4) + gA)*8192, H1 + ((((s+1)&1)<<4) + gA)*8192, tA, tid);
      sCommit(SA0, SA1, tA, tid);
      __syncthreads();
    }
  }

  // ================= zx = z @ dW_ih0 + biases, per stream =================
  if (tid == 0)  pollw(cntA, 32u*(u32)(TT+1));
  if (tid == 64) pollw(cntB, 32u*(u32)(TT+1));
  __syncthreads();
  sIssue(H1 + (16 + gA)*8192, H1 + (16 + gB)*8192, tA, tid);  // z = final enc1 h (parity 1)
  sCommit(SA0, SB0, tA, tid);                                  // SA0 <- zA, SB0 <- zB
  __syncthreads();
  f32x4 zxA, zxB;
  {
    f16x8 wZ[16];
#pragma unroll
    for (int k = 0; k < 16; ++k) wZ[k] = wfrag(dWih0, 512, srow, k, j);
    float zb = dbi0[srow] + dbh0[srow];
    zxA = f32x4{zb,zb,zb,zb}; zxB = f32x4{zb,zb,zb,zb};
#pragma unroll
    for (int k = 0; k < 16; ++k){
      zxA = MFMA16(*(const f16x8*)(SA0 + k*768 + abase), wZ[k], zxA);
      zxB = MFMA16(*(const f16x8*)(SB0 + k*768 + abase), wZ[k], zxB);
    }
  }

  // ---- decoder weights ----
#pragma unroll
  for (int k = 0; k < 16; ++k){
    wA[k] = wfrag(dWhh0, 512, srow, k, j);
    wB[k] = wfrag(dWih1, 512, srow, k, j);
    wC[k] = wfrag(dWhh1, 512, srow, k, j);
  }
#pragma unroll
  for (int e = 0; e < 4; ++e){
    int bi = (e<<9) + (cg<<4) + (w<<2) + hcc;
    B1r[e] = dbi1[bi] + dbh1[bi];
  }
  c0A = 0.f; c1A = 0.f; c0B = 0.f; c1B = 0.f;
  const u32 base = (u32)(TT + 1);

  // ================= decoder: same 2-stream interleave =================
  sIssue(D0 + gA*8192, D1 + gA*8192, tA, tid);   // parity 0 zeroed
  sCommit(SA0, SA1, tA, tid);
  __syncthreads();

  for (int s = 0; s <= TT; ++s){
    // --- half-step A ---
    Mdec(SA0, SA1, zxA, a0, a1);
    Ccell(s, true, a0, a1, c0A, c1A,
          D0 + ((((s+1)&1)<<4) + gA)*8192, D1 + ((((s+1)&1)<<4) + gA)*8192, b0A);
    __syncthreads();
    if (tid == 0)
      (void)__hip_atomic_fetch_add(cntA, 1u, __ATOMIC_RELAXED, __HIP_MEMORY_SCOPE_AGENT);
    if (tid == 64) pollw(cntB, 32u*(base + (u32)s));
    __syncthreads();
    sIssue(D0 + (((s&1)<<4) + gB)*8192, D1 + (((s&1)<<4) + gB)*8192, tB, tid);
    sCommit(SB0, SB1, tB, tid);
    __syncthreads();

    // --- half-step B ---
    Mdec(SB0, SB1, zxB, a0, a1);
    Ccell(s, true, a0, a1, c0B, c1B,
          D0 + ((((s+1)&1)<<4) + gB)*8192, D1 + ((((s+1)&1)<<4) + gB)*8192, b0B);
    __syncthreads();
    if (tid == 0)
      (void)__hip_atomic_fetch_add(cntB, 1u, __ATOMIC_RELAXED, __HIP_MEMORY_SCOPE_AGENT);
    if (s < TT){
      if (tid == 64) pollw(cntA, 32u*(base + (u32)(s+1)));
      __syncthreads();
      sIssue(D0 + ((((s+1)&1)<<4) + gA)*8192, D1 + ((((s+1)&1)<<4) + gA)*8192, tA, tid);
      sCommit(SA0, SA1, tA, tid);
      __syncthreads();
    }
  }

  // single acquire fence before plain HS reads
  __builtin_amdgcn_fence(__ATOMIC_ACQUIRE, "agent");
  __syncthreads();

  // ================= fc epilogue =================
  for (int qd = tid; qd < 8192; qd += 256){      // fcW [64][512] f32 -> f16 LDS overlay
    int i = qd >> 7, kq = qd & 127;
    float4 v = *(const float4*)(fcW + (i<<9) + (kq<<2));
    f16* p = (f16*)(lds + (i<<10) + (kq<<3));
    p[0]=(f16)v.x; p[1]=(f16)v.y; p[2]=(f16)v.z; p[3]=(f16)v.w;
  }
  __syncthreads();
  {
    int t  = (cg<<2) + w;                        // 32 cg x 4 waves = 128 timesteps
    int r  = lane >> 3;                          // 8 rows
    int iq = lane & 7;                           // 8 output chunks of 8
#pragma unroll
    for (int stq = 0; stq < 2; ++stq){
      int b0X = stq ? b0B : b0A;
      const char* hsrow = HS + (((t<<7) + b0X + r)<<10);
      float acc[8];
#pragma unroll
      for (int ii = 0; ii < 8; ++ii) acc[ii] = 0.f;
      for (int k8 = 0; k8 < 64; ++k8){
        f16x8 hv = *(const f16x8*)(hsrow + (k8<<4));
#pragma unroll
        for (int ii = 0; ii < 8; ++ii){
          f16x8 wv = *(const f16x8*)(lds + (((iq<<3)+ii)<<10) + (k8<<4));
#pragma unroll
          for (int jj = 0; jj < 8; ++jj) acc[ii] += (float)hv[jj] * (float)wv[jj];
        }
      }
#pragma unroll
      for (int ii = 0; ii < 8; ++ii){
        int i = (iq<<3) + ii;
        out[((((b0X+r)<<7) + t)<<6) + i] = acc[ii] + fcb[i];
      }
    }
  }
}

extern "C" void kernel_launch(void* const* d_in, const int* in_sizes, int n_in,
                              void* d_out, int out_size, void* d_ws, size_t ws_size,
                              hipStream_t stream){
  const float* x     = (const float*)d_in[0];
  const float* eWih0 = (const float*)d_in[1];
  const float* eWhh0 = (const float*)d_in[2];
  const float* ebi0  = (const float*)d_in[3];
  const float* ebh0  = (const float*)d_in[4];
  const float* eWih1 = (const float*)d_in[5];
  const float* eWhh1 = (const float*)d_in[6];
  const float* ebi1  = (const float*)d_in[7];
  const float* ebh1  = (const float*)d_in[8];
  const float* dWih0 = (const float*)d_in[9];
  const float* dWhh0 = (const float*)d_in[10];
  const float* dbi0  = (const float*)d_in[11];
  const float* dbh0  = (const float*)d_in[12];
  const float* dWih1 = (const float*)d_in[13];
  const float* dWhh1 = (const float*)d_in[14];
  const float* dbi1  = (const float*)d_in[15];
  const float* dbh1  = (const float*)d_in[16];
  const float* fcW   = (const float*)d_in[17];
  const float* fcb   = (const float*)d_in[18];
  char* ws = (char*)d_ws;

  hipMemsetAsync(d_ws, 0, OFF_XH, stream);       // zero counters + all h double-buffers
  cvt_x<<<512, 256, 0, stream>>>(x, ws);
  lstm_persist<<<256, 256, 0, stream>>>(eWih0,eWhh0,ebi0,ebh0,eWih1,eWhh1,ebi1,ebh1,
                                        dWih0,dWhh0,dbi0,dbh0,dWih1,dWhh1,dbi1,dbh1,
                                        fcW,fcb,(float*)d_out,ws);
}